// Round 17
// baseline (267.878 us; speedup 1.0000x reference)
//
#include <hip/hip_runtime.h>
#include <hip/hip_bf16.h>

#define HW    12288
#define Wimg  192
#define Himg  64
#define Wpad  194
#define Ppad  12804   // 66*194

// bf16 <-> fp32 helpers (RNE), header-independent
static __device__ __forceinline__ unsigned short f2bf(float f) {
    union { float f; unsigned int u; } v; v.f = f;
    unsigned int r = v.u + 0x7fffu + ((v.u >> 16) & 1u);
    return (unsigned short)(r >> 16);
}
static __device__ __forceinline__ float bf2f(unsigned short h) {
    union { unsigned int u; float f; } v; v.u = ((unsigned int)h) << 16;
    return v.f;
}
static __device__ __forceinline__ float bflo(unsigned int u) {
    union { unsigned int u; float f; } v; v.u = u << 16; return v.f;
}
static __device__ __forceinline__ float bfhi(unsigned int u) {
    union { unsigned int u; float f; } v; v.u = u & 0xffff0000u; return v.f;
}

// ---------------------------------------------------------------------------
// K1: deformable gather via LDS-staged windows (flat-space staging, R15/R16).
// ---------------------------------------------------------------------------
__global__ __launch_bounds__(256, 4) void k_deform(
    const float* __restrict__ x,     // 256 x HW
    const float* __restrict__ xr,    // HW
    const float* __restrict__ rout,  // 256 x 9
    unsigned short* __restrict__ y0) // 256 x HW (bf16)
{
    __shared__ float s_x[32][240];   // 3 window rows x stride 80 (74 used)

    const int cblk = blockIdx.x;     // 0..7   (fastest -> XCD id)
    const int tile = blockIdx.y;     // 0..191
    const int tid  = threadIdx.x;
    const int pl   = tid & 63;
    const int wv   = __builtin_amdgcn_readfirstlane(tid >> 6);
    const int h    = tile / 3;
    const int w0   = (tile - h * 3) * 64;
    const int w    = w0 + pl;
    const int gp   = h * Wimg + w;

    int   li[6];
    float gw[6][3];
    const float off = 3.0f / (1.0f + expf(-xr[gp]));

    #pragma unroll
    for (int t = 0; t < 6; ++t) {
        const int xo = (t & 1) ? 1 : -1;
        const int yo = (t >> 1) - 1;
        float ov  = off * (float)xo;
        int   iv  = yo * Wpad;
        int   pre = (h + 1) * Wpad + (w + 1) + xo + iv;
        float after = (float)(pre + iv) + ov;
        int fl = (int)floorf(ov);
        int ce = (int)ceilf(ov);
        int av_f  = min(max(pre + fl + iv, 0), Ppad - 1);
        int av_f1 = min(max(av_f + xo,    0), Ppad - 1);
        int av_c  = min(max(pre + ce + iv, 0), Ppad - 1);
        int av_c1 = min(max(av_c + xo,    0), Ppad - 1);
        float wf  = fabsf(after - (float)av_f);
        float wf1 = fabsf((float)av_f1 - after);
        float wc1 = fabsf(after - (float)av_c1);
        float wc  = fabsf((float)av_c - after);
        float s1 = wf  * (1.0f / Wpad);
        float s2 = wc1 * (1.0f / Wpad);
        int   i4[4] = { av_f, av_f1, av_c1, av_c };
        float w4[4] = { s1 * wf, s1 * wf1, s2 * wc1, s2 * wc };
        int b = min(min(i4[0], i4[1]), min(i4[2], i4[3]));
        const int base = (h + 1 + 2 * yo) * Wpad + w0 - 4;
        li[t] = (t >> 1) * 80 + min(max(b - base, 0), 71);
        #pragma unroll
        for (int s = 0; s < 3; ++s) {
            float ws = 0.0f;
            #pragma unroll
            for (int j = 0; j < 4; ++j)
                ws += (i4[j] == b + s) ? w4[j] : 0.0f;
            int av = b + s;
            int r  = av / Wpad;
            int cc = av - r * Wpad;
            bool inb = (r >= 1) && (r <= Himg) && (cc >= 1) && (cc <= Wimg);
            gw[t][s] = inb ? ws : 0.0f;
        }
    }

    const int jj = tid;
    int  xoff = 0;
    bool valid = false;
    int  rr = 0, jcol = 0;
    if (jj < 222) {
        rr   = jj / 74;
        jcol = jj - rr * 74;
        const int flat = (h + 1 + 2 * (rr - 1)) * Wpad + w0 - 4 + jcol;
        if (flat >= 0 && flat < Ppad) {
            const int r = flat / Wpad;
            const int c = flat - r * Wpad;
            valid = (r >= 1) && (r <= Himg) && (c >= 1) && (c <= Wimg);
            xoff  = valid ? ((r - 1) * Wimg + (c - 1)) : 0;
        }
    }
    const float* xb = x + (size_t)(cblk * 32) * HW;
    for (int c = 0; c < 32; ++c) {
        if (jj < 222) {
            float v = valid ? xb[(size_t)c * HW + xoff] : 0.0f;
            s_x[c][rr * 80 + jcol] = v;
        }
    }
    __syncthreads();

    const int c0l = wv * 8;
    #pragma unroll 2
    for (int i = 0; i < 8; ++i) {
        const int cl = c0l + i;
        const float* sxc = s_x[cl];
        const float* rc  = rout + (cblk * 32 + cl) * 9;
        float acc = 0.0f;
        #pragma unroll
        for (int t = 0; t < 6; ++t) {
            float part = gw[t][0] * sxc[li[t]]
                       + gw[t][1] * sxc[li[t] + 1]
                       + gw[t][2] * sxc[li[t] + 2];
            const int k = 3 * (t >> 1) + ((t & 1) ? 2 : 0);
            acc += rc[k] * part;
        }
        y0[(size_t)(cblk * 32 + cl) * HW + gp] = f2bf(acc);
    }
}

// ---------------------------------------------------------------------------
// Pointwise GEMM (layer 1), split-K, bf16 in/out (R16-proven).
// ---------------------------------------------------------------------------
template <int CIN>
__global__ __launch_bounds__(256) void k_pw(
    const unsigned short* __restrict__ A,   // CIN x HW (bf16)
    const float* __restrict__ Wm,           // 128 x CIN (fp32)
    unsigned short* __restrict__ Zp0,
    unsigned short* __restrict__ Zp1)
{
    __shared__ float s_a[32][64];
    __shared__ float s_w[32][68];
    const int tid = threadIdx.x;
    const int tx  = tid & 15;
    const int ty  = tid >> 4;
    const int px0 = blockIdx.x * 64;
    const int o0  = blockIdx.y * 64;
    const int KH  = CIN / 2;
    const int cb0 = blockIdx.z * KH;
    unsigned short* __restrict__ Zp = blockIdx.z ? Zp1 : Zp0;

    float acc[4][4];
    #pragma unroll
    for (int i = 0; i < 4; ++i)
        #pragma unroll
        for (int j = 0; j < 4; ++j) acc[i][j] = 0.0f;

    const int arow = tid >> 3;
    const int acg  = tid & 7;
    const int wo = tid >> 5;
    const int wl = tid & 31;

    for (int cb = cb0; cb < cb0 + KH; cb += 32) {
        {
            const uint4* ap = (const uint4*)(A + (size_t)(cb + arow) * HW + px0);
            uint4 u = ap[acg];
            float4 lo = make_float4(bflo(u.x), bfhi(u.x), bflo(u.y), bfhi(u.y));
            float4 hi = make_float4(bflo(u.z), bfhi(u.z), bflo(u.w), bfhi(u.w));
            *(float4*)&s_a[arow][acg * 8]     = lo;
            *(float4*)&s_a[arow][acg * 8 + 4] = hi;
        }
        #pragma unroll
        for (int i = 0; i < 8; ++i)
            s_w[wl][wo + 8 * i] = Wm[(size_t)(o0 + wo + 8 * i) * CIN + cb + wl];
        __syncthreads();
        #pragma unroll
        for (int cc = 0; cc < 32; ++cc) {
            float4 a4 = *(const float4*)&s_a[cc][tx * 4];
            float4 w4 = *(const float4*)&s_w[cc][ty * 4];
            acc[0][0] += w4.x * a4.x; acc[0][1] += w4.x * a4.y;
            acc[0][2] += w4.x * a4.z; acc[0][3] += w4.x * a4.w;
            acc[1][0] += w4.y * a4.x; acc[1][1] += w4.y * a4.y;
            acc[1][2] += w4.y * a4.z; acc[1][3] += w4.y * a4.w;
            acc[2][0] += w4.z * a4.x; acc[2][1] += w4.z * a4.y;
            acc[2][2] += w4.z * a4.z; acc[2][3] += w4.z * a4.w;
            acc[3][0] += w4.w * a4.x; acc[3][1] += w4.w * a4.y;
            acc[3][2] += w4.w * a4.z; acc[3][3] += w4.w * a4.w;
        }
        __syncthreads();
    }

    #pragma unroll
    for (int i = 0; i < 4; ++i) {
        ushort4 v;
        v.x = f2bf(acc[i][0]); v.y = f2bf(acc[i][1]);
        v.z = f2bf(acc[i][2]); v.w = f2bf(acc[i][3]);
        *(ushort4*)&Zp[(size_t)(o0 + ty * 4 + i) * HW + px0 + tx * 4] = v;
    }
}

// ---------------------------------------------------------------------------
// BN stats over z = Zp0 + Zp1 (no z write).  grid = (128 ch x 4 segments).
// ---------------------------------------------------------------------------
__global__ __launch_bounds__(256) void k_stats(
    const unsigned short* __restrict__ Zp0,
    const unsigned short* __restrict__ Zp1,
    float* __restrict__ psum)        // 128 x {sum,sumsq}, pre-zeroed
{
    __shared__ float s_s[4], s_q[4];
    const int c   = blockIdx.x >> 2;
    const int seg = blockIdx.x & 3;
    const int tid = threadIdx.x;
    const size_t base = (size_t)c * HW + seg * 3072;
    const uint2* a4 = (const uint2*)(Zp0 + base);
    const uint2* b4 = (const uint2*)(Zp1 + base);
    float s = 0.0f, q = 0.0f;
    #pragma unroll
    for (int i = 0; i < 3; ++i) {
        uint2 a = a4[tid + i * 256];
        uint2 b = b4[tid + i * 256];
        float v0 = bflo(a.x) + bflo(b.x);
        float v1 = bfhi(a.x) + bfhi(b.x);
        float v2 = bflo(a.y) + bflo(b.y);
        float v3 = bfhi(a.y) + bfhi(b.y);
        s += v0 + v1 + v2 + v3;
        q += v0 * v0 + v1 * v1 + v2 * v2 + v3 * v3;
    }
    #pragma unroll
    for (int off = 32; off > 0; off >>= 1) {
        s += __shfl_down(s, off, 64);
        q += __shfl_down(q, off, 64);
    }
    if ((tid & 63) == 0) { s_s[tid >> 6] = s; s_q[tid >> 6] = q; }
    __syncthreads();
    if (tid == 0) {
        s = s_s[0] + s_s[1] + s_s[2] + s_s[3];
        q = s_q[0] + s_q[1] + s_q[2] + s_q[3];
        atomicAdd(&psum[2 * c],     s);
        atomicAdd(&psum[2 * c + 1], q);
    }
}

// ---------------------------------------------------------------------------
// FUSED: BN+LeakyReLU + depthwise 3x3 + pointwise 128x128 GEMM, split-K.
// Block = 64 px x 64 outs x K-half, grid (192,2,2).  Per 32-ch chunk:
//  (1) stage z = Zp0+Zp1 neighborhood (3 rows x 66 cols), BN+act inline ->
//      s_z;  (2) depthwise 3x3 -> s_a (px = (tid&7)+8k: conflict-free);
//  (3) proven 4x4 FMA loop.  d / z never touch global memory.
// ---------------------------------------------------------------------------
__global__ __launch_bounds__(256) void k_pwdw(
    const unsigned short* __restrict__ Zp0,  // prev partial pair (bf16)
    const unsigned short* __restrict__ Zp1,
    const float* __restrict__ psum,          // stats of z
    const float* __restrict__ g,
    const float* __restrict__ b,
    const float* __restrict__ dwgt,          // 128 x 9
    const float* __restrict__ Wm,            // 128 x 128 (pointwise)
    unsigned short* __restrict__ Zq0,        // next partial pair (bf16)
    unsigned short* __restrict__ Zq1)
{
    __shared__ float s_z[3][32][68];
    __shared__ float s_a[32][68];    // stride 68: float4-aligned, bank-spread
    __shared__ float s_w[32][68];
    __shared__ float s_sc[64], s_sh[64];

    const int tid = threadIdx.x;
    const int tx  = tid & 15;
    const int ty  = tid >> 4;
    const int h   = blockIdx.x / 3;
    const int w0  = (blockIdx.x - h * 3) * 64;
    const int px0 = h * Wimg + w0;   // == blockIdx.x * 64
    const int o0  = blockIdx.y * 64;
    const int bz  = blockIdx.z;
    unsigned short* __restrict__ Zq = bz ? Zq1 : Zq0;

    if (tid < 64) {
        const int ci = bz * 64 + tid;
        const float s  = psum[2 * ci];
        const float q  = psum[2 * ci + 1];
        const float mu = s * (1.0f / HW);
        const float var = q * (1.0f / HW) - mu * mu;
        const float sc = g[ci] * rsqrtf(var + 1e-5f);
        s_sc[tid] = sc;
        s_sh[tid] = b[ci] - mu * sc;
    }
    __syncthreads();

    float acc[4][4];
    #pragma unroll
    for (int i = 0; i < 4; ++i)
        #pragma unroll
        for (int j = 0; j < 4; ++j) acc[i][j] = 0.0f;

    const int wo = tid >> 5;
    const int wl = tid & 31;

    for (int ck = 0; ck < 2; ++ck) {
        const int cl0 = ck * 32;
        // (1) stage activated z neighborhood: 3 x 32 x 68 slots
        #pragma unroll
        for (int j = 0; j < 26; ++j) {
            const int idx = tid + j * 256;
            if (idx < 6528) {
                const int r   = idx / 2176;
                const int rem = idx - r * 2176;
                const int c   = rem / 68;
                const int col = rem - c * 68;
                float y = 0.0f;
                if (col < 66) {
                    const int grow = h - 1 + r;
                    const int gcol = w0 - 1 + col;
                    if (grow >= 0 && grow < Himg && gcol >= 0 && gcol < Wimg) {
                        const int ci = bz * 64 + cl0 + c;
                        const size_t off = (size_t)ci * HW + grow * Wimg + gcol;
                        float z = bf2f(Zp0[off]) + bf2f(Zp1[off]);
                        y = z * s_sc[cl0 + c] + s_sh[cl0 + c];
                        y = (y >= 0.0f) ? y : 0.01f * y;
                    }
                }
                s_z[r][c][col] = y;
            }
        }
        // stage pointwise W for this chunk
        #pragma unroll
        for (int i = 0; i < 8; ++i)
            s_w[wl][wo + 8 * i] =
                Wm[(size_t)(o0 + wo + 8 * i) * 128 + bz * 64 + cl0 + wl];
        __syncthreads();

        // (2) depthwise 3x3 -> s_a
        {
            const int c  = tid >> 3;
            const int p0 = tid & 7;
            const int ci = bz * 64 + cl0 + c;
            float wk[9];
            #pragma unroll
            for (int k = 0; k < 9; ++k) wk[k] = dwgt[ci * 9 + k];
            #pragma unroll
            for (int k = 0; k < 8; ++k) {
                const int px = p0 + 8 * k;
                float a = 0.0f;
                #pragma unroll
                for (int ky = 0; ky < 3; ++ky)
                    #pragma unroll
                    for (int kx = 0; kx < 3; ++kx)
                        a += wk[ky * 3 + kx] * s_z[ky][c][px + kx];
                s_a[c][px] = a;
            }
        }
        __syncthreads();

        // (3) FMA loop
        #pragma unroll
        for (int cc = 0; cc < 32; ++cc) {
            float4 a4 = *(const float4*)&s_a[cc][tx * 4];
            float4 w4 = *(const float4*)&s_w[cc][ty * 4];
            acc[0][0] += w4.x * a4.x; acc[0][1] += w4.x * a4.y;
            acc[0][2] += w4.x * a4.z; acc[0][3] += w4.x * a4.w;
            acc[1][0] += w4.y * a4.x; acc[1][1] += w4.y * a4.y;
            acc[1][2] += w4.y * a4.z; acc[1][3] += w4.y * a4.w;
            acc[2][0] += w4.z * a4.x; acc[2][1] += w4.z * a4.y;
            acc[2][2] += w4.z * a4.z; acc[2][3] += w4.z * a4.w;
            acc[3][0] += w4.w * a4.x; acc[3][1] += w4.w * a4.y;
            acc[3][2] += w4.w * a4.z; acc[3][3] += w4.w * a4.w;
        }
        __syncthreads();
    }

    #pragma unroll
    for (int i = 0; i < 4; ++i) {
        ushort4 v;
        v.x = f2bf(acc[i][0]); v.y = f2bf(acc[i][1]);
        v.z = f2bf(acc[i][2]); v.w = f2bf(acc[i][3]);
        *(ushort4*)&Zq[(size_t)(o0 + ty * 4 + i) * HW + px0 + tx * 4] = v;
    }
}

// ---------------------------------------------------------------------------
// Final: z = Zp0+Zp1, BN+LeakyReLU, fp32 out.  grid = 1536.
// ---------------------------------------------------------------------------
__global__ __launch_bounds__(256) void k_final2(
    const unsigned short* __restrict__ Zp0,
    const unsigned short* __restrict__ Zp1,
    const float* __restrict__ psum,
    const float* __restrict__ g,
    const float* __restrict__ b,
    float4* __restrict__ out)
{
    const int f = blockIdx.x * 256 + threadIdx.x;
    const int c = f / 3072;

    const float s   = psum[2 * c];
    const float q   = psum[2 * c + 1];
    const float mu  = s * (1.0f / HW);
    const float var = q * (1.0f / HW) - mu * mu;
    const float sc  = g[c] * rsqrtf(var + 1e-5f);
    const float sh  = b[c] - mu * sc;

    uint2 a = ((const uint2*)Zp0)[f];
    uint2 d = ((const uint2*)Zp1)[f];
    float4 v;
    v.x = (bflo(a.x) + bflo(d.x)) * sc + sh; v.x = (v.x >= 0.0f) ? v.x : 0.01f * v.x;
    v.y = (bfhi(a.x) + bfhi(d.x)) * sc + sh; v.y = (v.y >= 0.0f) ? v.y : 0.01f * v.y;
    v.z = (bflo(a.y) + bflo(d.y)) * sc + sh; v.z = (v.z >= 0.0f) ? v.z : 0.01f * v.z;
    v.w = (bfhi(a.y) + bfhi(d.y)) * sc + sh; v.w = (v.w >= 0.0f) ? v.w : 0.01f * v.w;
    out[f] = v;
}

// ---------------------------------------------------------------------------
extern "C" void kernel_launch(void* const* d_in, const int* in_sizes, int n_in,
                              void* d_out, int out_size, void* d_ws, size_t ws_size,
                              hipStream_t stream) {
    const float* x   = (const float*)d_in[0];
    const float* xr  = (const float*)d_in[1];
    const float* ro  = (const float*)d_in[2];
    const float* wr  = (const float*)d_in[3];
    const float* gr  = (const float*)d_in[4];
    const float* br  = (const float*)d_in[5];
    const float* dw1 = (const float*)d_in[6];
    const float* pw1 = (const float*)d_in[7];
    const float* g1  = (const float*)d_in[8];
    const float* b1  = (const float*)d_in[9];
    const float* dw2 = (const float*)d_in[10];
    const float* pw2 = (const float*)d_in[11];
    const float* g2  = (const float*)d_in[12];
    const float* b2  = (const float*)d_in[13];

    unsigned short* WS = (unsigned short*)d_ws;
    // bf16 buffers (ushort offsets):
    //   y0  = [0, 3145728)
    //   P0a = [3145728, 4718592), P0b = [4718592, 6291456)
    //   P1a = [6291456, 7864320), P1b = [7864320, 9437184)
    //   float psums at ushort 9437184 (byte 18874368)
    unsigned short* y0  = WS;
    unsigned short* P0a = WS + 3145728;
    unsigned short* P0b = WS + 4718592;
    unsigned short* P1a = WS + 6291456;
    unsigned short* P1b = WS + 7864320;
    float* p1 = (float*)(WS + 9437184);
    float* p2 = p1 + 256;
    float* p3 = p2 + 256;
    float* out = (float*)d_out;

    hipMemsetAsync(p1, 0, 768 * 4, stream);            // p1,p2,p3

    k_deform<<<dim3(8, 192), 256, 0, stream>>>(x, xr, ro, y0);
    k_pw<256><<<dim3(192, 2, 2), 256, 0, stream>>>(y0, wr, P0a, P0b);
    k_stats<<<512, 256, 0, stream>>>(P0a, P0b, p1);
    k_pwdw<<<dim3(192, 2, 2), 256, 0, stream>>>(P0a, P0b, p1, gr, br, dw1, pw1,
                                                P1a, P1b);
    k_stats<<<512, 256, 0, stream>>>(P1a, P1b, p2);
    k_pwdw<<<dim3(192, 2, 2), 256, 0, stream>>>(P1a, P1b, p2, g1, b1, dw2, pw2,
                                                P0a, P0b);
    k_stats<<<512, 256, 0, stream>>>(P0a, P0b, p3);
    k_final2<<<1536, 256, 0, stream>>>(P0a, P0b, p3, g2, b2, (float4*)out);
}

// Round 18
// 172.367 us; speedup vs baseline: 1.5541x; 1.5541x over previous
//
#include <hip/hip_runtime.h>
#include <hip/hip_bf16.h>

#define HW    12288
#define Wimg  192
#define Himg  64
#define Wpad  194
#define Ppad  12804   // 66*194

// bf16 <-> fp32 helpers (RNE), header-independent
static __device__ __forceinline__ unsigned short f2bf(float f) {
    union { float f; unsigned int u; } v; v.f = f;
    unsigned int r = v.u + 0x7fffu + ((v.u >> 16) & 1u);
    return (unsigned short)(r >> 16);
}
static __device__ __forceinline__ float bf2f(unsigned short h) {
    union { unsigned int u; float f; } v; v.u = ((unsigned int)h) << 16;
    return v.f;
}
static __device__ __forceinline__ float bflo(unsigned int u) {
    union { unsigned int u; float f; } v; v.u = u << 16; return v.f;
}
static __device__ __forceinline__ float bfhi(unsigned int u) {
    union { unsigned int u; float f; } v; v.u = u & 0xffff0000u; return v.f;
}

// ---------------------------------------------------------------------------
// K1: deformable gather via LDS-staged windows (flat-space staging, R15/R16).
// ---------------------------------------------------------------------------
__global__ __launch_bounds__(256, 4) void k_deform(
    const float* __restrict__ x,     // 256 x HW
    const float* __restrict__ xr,    // HW
    const float* __restrict__ rout,  // 256 x 9
    unsigned short* __restrict__ y0) // 256 x HW (bf16)
{
    __shared__ float s_x[32][240];   // 3 window rows x stride 80 (74 used)

    const int cblk = blockIdx.x;     // 0..7   (fastest -> XCD id)
    const int tile = blockIdx.y;     // 0..191
    const int tid  = threadIdx.x;
    const int pl   = tid & 63;
    const int wv   = __builtin_amdgcn_readfirstlane(tid >> 6);
    const int h    = tile / 3;
    const int w0   = (tile - h * 3) * 64;
    const int w    = w0 + pl;
    const int gp   = h * Wimg + w;

    int   li[6];
    float gw[6][3];
    const float off = 3.0f / (1.0f + expf(-xr[gp]));

    #pragma unroll
    for (int t = 0; t < 6; ++t) {
        const int xo = (t & 1) ? 1 : -1;
        const int yo = (t >> 1) - 1;
        float ov  = off * (float)xo;
        int   iv  = yo * Wpad;
        int   pre = (h + 1) * Wpad + (w + 1) + xo + iv;
        float after = (float)(pre + iv) + ov;
        int fl = (int)floorf(ov);
        int ce = (int)ceilf(ov);
        int av_f  = min(max(pre + fl + iv, 0), Ppad - 1);
        int av_f1 = min(max(av_f + xo,    0), Ppad - 1);
        int av_c  = min(max(pre + ce + iv, 0), Ppad - 1);
        int av_c1 = min(max(av_c + xo,    0), Ppad - 1);
        float wf  = fabsf(after - (float)av_f);
        float wf1 = fabsf((float)av_f1 - after);
        float wc1 = fabsf(after - (float)av_c1);
        float wc  = fabsf((float)av_c - after);
        float s1 = wf  * (1.0f / Wpad);
        float s2 = wc1 * (1.0f / Wpad);
        int   i4[4] = { av_f, av_f1, av_c1, av_c };
        float w4[4] = { s1 * wf, s1 * wf1, s2 * wc1, s2 * wc };
        int b = min(min(i4[0], i4[1]), min(i4[2], i4[3]));
        const int base = (h + 1 + 2 * yo) * Wpad + w0 - 4;
        li[t] = (t >> 1) * 80 + min(max(b - base, 0), 71);
        #pragma unroll
        for (int s = 0; s < 3; ++s) {
            float ws = 0.0f;
            #pragma unroll
            for (int j = 0; j < 4; ++j)
                ws += (i4[j] == b + s) ? w4[j] : 0.0f;
            int av = b + s;
            int r  = av / Wpad;
            int cc = av - r * Wpad;
            bool inb = (r >= 1) && (r <= Himg) && (cc >= 1) && (cc <= Wimg);
            gw[t][s] = inb ? ws : 0.0f;
        }
    }

    const int jj = tid;
    int  xoff = 0;
    bool valid = false;
    int  rr = 0, jcol = 0;
    if (jj < 222) {
        rr   = jj / 74;
        jcol = jj - rr * 74;
        const int flat = (h + 1 + 2 * (rr - 1)) * Wpad + w0 - 4 + jcol;
        if (flat >= 0 && flat < Ppad) {
            const int r = flat / Wpad;
            const int c = flat - r * Wpad;
            valid = (r >= 1) && (r <= Himg) && (c >= 1) && (c <= Wimg);
            xoff  = valid ? ((r - 1) * Wimg + (c - 1)) : 0;
        }
    }
    const float* xb = x + (size_t)(cblk * 32) * HW;
    for (int c = 0; c < 32; ++c) {
        if (jj < 222) {
            float v = valid ? xb[(size_t)c * HW + xoff] : 0.0f;
            s_x[c][rr * 80 + jcol] = v;
        }
    }
    __syncthreads();

    const int c0l = wv * 8;
    #pragma unroll 2
    for (int i = 0; i < 8; ++i) {
        const int cl = c0l + i;
        const float* sxc = s_x[cl];
        const float* rc  = rout + (cblk * 32 + cl) * 9;
        float acc = 0.0f;
        #pragma unroll
        for (int t = 0; t < 6; ++t) {
            float part = gw[t][0] * sxc[li[t]]
                       + gw[t][1] * sxc[li[t] + 1]
                       + gw[t][2] * sxc[li[t] + 2];
            const int k = 3 * (t >> 1) + ((t & 1) ? 2 : 0);
            acc += rc[k] * part;
        }
        y0[(size_t)(cblk * 32 + cl) * HW + gp] = f2bf(acc);
    }
}

// ---------------------------------------------------------------------------
// Pointwise GEMM, split-K, bf16 in/out (R16-proven).
// ---------------------------------------------------------------------------
template <int CIN>
__global__ __launch_bounds__(256) void k_pw(
    const unsigned short* __restrict__ A,   // CIN x HW (bf16)
    const float* __restrict__ Wm,           // 128 x CIN (fp32)
    unsigned short* __restrict__ Zp0,
    unsigned short* __restrict__ Zp1)
{
    __shared__ float s_a[32][64];
    __shared__ float s_w[32][68];
    const int tid = threadIdx.x;
    const int tx  = tid & 15;
    const int ty  = tid >> 4;
    const int px0 = blockIdx.x * 64;
    const int o0  = blockIdx.y * 64;
    const int KH  = CIN / 2;
    const int cb0 = blockIdx.z * KH;
    unsigned short* __restrict__ Zp = blockIdx.z ? Zp1 : Zp0;

    float acc[4][4];
    #pragma unroll
    for (int i = 0; i < 4; ++i)
        #pragma unroll
        for (int j = 0; j < 4; ++j) acc[i][j] = 0.0f;

    const int arow = tid >> 3;
    const int acg  = tid & 7;
    const int wo = tid >> 5;
    const int wl = tid & 31;

    for (int cb = cb0; cb < cb0 + KH; cb += 32) {
        {
            const uint4* ap = (const uint4*)(A + (size_t)(cb + arow) * HW + px0);
            uint4 u = ap[acg];
            float4 lo = make_float4(bflo(u.x), bfhi(u.x), bflo(u.y), bfhi(u.y));
            float4 hi = make_float4(bflo(u.z), bfhi(u.z), bflo(u.w), bfhi(u.w));
            *(float4*)&s_a[arow][acg * 8]     = lo;
            *(float4*)&s_a[arow][acg * 8 + 4] = hi;
        }
        #pragma unroll
        for (int i = 0; i < 8; ++i)
            s_w[wl][wo + 8 * i] = Wm[(size_t)(o0 + wo + 8 * i) * CIN + cb + wl];
        __syncthreads();
        #pragma unroll
        for (int cc = 0; cc < 32; ++cc) {
            float4 a4 = *(const float4*)&s_a[cc][tx * 4];
            float4 w4 = *(const float4*)&s_w[cc][ty * 4];
            acc[0][0] += w4.x * a4.x; acc[0][1] += w4.x * a4.y;
            acc[0][2] += w4.x * a4.z; acc[0][3] += w4.x * a4.w;
            acc[1][0] += w4.y * a4.x; acc[1][1] += w4.y * a4.y;
            acc[1][2] += w4.y * a4.z; acc[1][3] += w4.y * a4.w;
            acc[2][0] += w4.z * a4.x; acc[2][1] += w4.z * a4.y;
            acc[2][2] += w4.z * a4.z; acc[2][3] += w4.z * a4.w;
            acc[3][0] += w4.w * a4.x; acc[3][1] += w4.w * a4.y;
            acc[3][2] += w4.w * a4.z; acc[3][3] += w4.w * a4.w;
        }
        __syncthreads();
    }

    #pragma unroll
    for (int i = 0; i < 4; ++i) {
        ushort4 v;
        v.x = f2bf(acc[i][0]); v.y = f2bf(acc[i][1]);
        v.z = f2bf(acc[i][2]); v.w = f2bf(acc[i][3]);
        *(ushort4*)&Zp[(size_t)(o0 + ty * 4 + i) * HW + px0 + tx * 4] = v;
    }
}

// ---------------------------------------------------------------------------
// BN stats over z = Zp0 + Zp1.  One block per channel, direct write
// (no atomics, no memset needed).  grid = 128.
// ---------------------------------------------------------------------------
__global__ __launch_bounds__(256) void k_stats2(
    const unsigned short* __restrict__ Zp0,
    const unsigned short* __restrict__ Zp1,
    float* __restrict__ psum)        // 128 x {sum,sumsq}
{
    __shared__ float s_s[4], s_q[4];
    const int c   = blockIdx.x;
    const int tid = threadIdx.x;
    const size_t base = (size_t)c * HW;
    const uint2* a4 = (const uint2*)(Zp0 + base);
    const uint2* b4 = (const uint2*)(Zp1 + base);
    float s = 0.0f, q = 0.0f;
    #pragma unroll
    for (int i = 0; i < 12; ++i) {
        uint2 a = a4[tid + i * 256];
        uint2 b = b4[tid + i * 256];
        float v0 = bflo(a.x) + bflo(b.x);
        float v1 = bfhi(a.x) + bfhi(b.x);
        float v2 = bflo(a.y) + bflo(b.y);
        float v3 = bfhi(a.y) + bfhi(b.y);
        s += v0 + v1 + v2 + v3;
        q += v0 * v0 + v1 * v1 + v2 * v2 + v3 * v3;
    }
    #pragma unroll
    for (int off = 32; off > 0; off >>= 1) {
        s += __shfl_down(s, off, 64);
        q += __shfl_down(q, off, 64);
    }
    if ((tid & 63) == 0) { s_s[tid >> 6] = s; s_q[tid >> 6] = q; }
    __syncthreads();
    if (tid == 0) {
        psum[2 * c]     = s_s[0] + s_s[1] + s_s[2] + s_s[3];
        psum[2 * c + 1] = s_q[0] + s_q[1] + s_q[2] + s_q[3];
    }
}

// ---------------------------------------------------------------------------
// Fused: z = Zp0+Zp1 (inline), BN+LeakyReLU, depthwise 3x3 (zero pad).
// 4 px / thread; bf16 out.  grid = 1536.
// ---------------------------------------------------------------------------
__global__ __launch_bounds__(256) void k_dw2(
    const unsigned short* __restrict__ Zp0,
    const unsigned short* __restrict__ Zp1,
    const float* __restrict__ psum,  // 128 x {sum,sumsq}
    const float* __restrict__ g,
    const float* __restrict__ b,
    const float* __restrict__ dwgt,  // 128 x 9
    ushort4* __restrict__ D)
{
    const int t  = blockIdx.x * 256 + threadIdx.x;  // 0..393215
    const int c  = t / 3072;
    const int gg = t - c * 3072;
    const int h  = gg / 48;
    const int w0 = (gg - h * 48) << 2;

    const float s   = psum[2 * c];
    const float q   = psum[2 * c + 1];
    const float mu  = s * (1.0f / HW);
    const float var = q * (1.0f / HW) - mu * mu;
    const float sc  = g[c] * rsqrtf(var + 1e-5f);
    const float sh  = b[c] - mu * sc;

    float wk[9];
    #pragma unroll
    for (int k = 0; k < 9; ++k) wk[k] = dwgt[c * 9 + k];

    const unsigned short* z0 = Zp0 + (size_t)c * HW;
    const unsigned short* z1 = Zp1 + (size_t)c * HW;
    float v[3][6];
    #pragma unroll
    for (int ky = 0; ky < 3; ++ky) {
        const int hh  = h + ky - 1;
        const bool rin = (hh >= 0) && (hh < Himg);
        #pragma unroll
        for (int j = 0; j < 6; ++j) {
            const int ww = w0 - 1 + j;
            const bool in = rin && (ww >= 0) && (ww < Wimg);
            float z = in ? (bf2f(z0[hh * Wimg + ww]) + bf2f(z1[hh * Wimg + ww]))
                         : 0.0f;
            float y = z * sc + sh;
            y = (y >= 0.0f) ? y : 0.01f * y;
            v[ky][j] = in ? y : 0.0f;
        }
    }

    ushort4 o;
    float oo[4];
    #pragma unroll
    for (int j = 0; j < 4; ++j) {
        float a = 0.0f;
        #pragma unroll
        for (int ky = 0; ky < 3; ++ky)
            #pragma unroll
            for (int kx = 0; kx < 3; ++kx)
                a += wk[ky * 3 + kx] * v[ky][j + kx];
        oo[j] = a;
    }
    o.x = f2bf(oo[0]); o.y = f2bf(oo[1]); o.z = f2bf(oo[2]); o.w = f2bf(oo[3]);
    D[t] = o;
}

// ---------------------------------------------------------------------------
// Final: z = Zp0+Zp1, BN+LeakyReLU, fp32 out.  grid = 1536.
// ---------------------------------------------------------------------------
__global__ __launch_bounds__(256) void k_final2(
    const unsigned short* __restrict__ Zp0,
    const unsigned short* __restrict__ Zp1,
    const float* __restrict__ psum,
    const float* __restrict__ g,
    const float* __restrict__ b,
    float4* __restrict__ out)
{
    const int f = blockIdx.x * 256 + threadIdx.x;
    const int c = f / 3072;

    const float s   = psum[2 * c];
    const float q   = psum[2 * c + 1];
    const float mu  = s * (1.0f / HW);
    const float var = q * (1.0f / HW) - mu * mu;
    const float sc  = g[c] * rsqrtf(var + 1e-5f);
    const float sh  = b[c] - mu * sc;

    uint2 a = ((const uint2*)Zp0)[f];
    uint2 d = ((const uint2*)Zp1)[f];
    float4 v;
    v.x = (bflo(a.x) + bflo(d.x)) * sc + sh; v.x = (v.x >= 0.0f) ? v.x : 0.01f * v.x;
    v.y = (bfhi(a.x) + bfhi(d.x)) * sc + sh; v.y = (v.y >= 0.0f) ? v.y : 0.01f * v.y;
    v.z = (bflo(a.y) + bflo(d.y)) * sc + sh; v.z = (v.z >= 0.0f) ? v.z : 0.01f * v.z;
    v.w = (bfhi(a.y) + bfhi(d.y)) * sc + sh; v.w = (v.w >= 0.0f) ? v.w : 0.01f * v.w;
    out[f] = v;
}

// ---------------------------------------------------------------------------
extern "C" void kernel_launch(void* const* d_in, const int* in_sizes, int n_in,
                              void* d_out, int out_size, void* d_ws, size_t ws_size,
                              hipStream_t stream) {
    const float* x   = (const float*)d_in[0];
    const float* xr  = (const float*)d_in[1];
    const float* ro  = (const float*)d_in[2];
    const float* wr  = (const float*)d_in[3];
    const float* gr  = (const float*)d_in[4];
    const float* br  = (const float*)d_in[5];
    const float* dw1 = (const float*)d_in[6];
    const float* pw1 = (const float*)d_in[7];
    const float* g1  = (const float*)d_in[8];
    const float* b1  = (const float*)d_in[9];
    const float* dw2 = (const float*)d_in[10];
    const float* pw2 = (const float*)d_in[11];
    const float* g2  = (const float*)d_in[12];
    const float* b2  = (const float*)d_in[13];

    unsigned short* WS = (unsigned short*)d_ws;
    // bf16 buffers (ushort offsets):
    //   y0  = [0, 3145728)          (dead after pw256; D reuses [0,1572864))
    //   P0a = [3145728, 4718592), P0b = [4718592, 6291456)
    //   P1a = [6291456, 7864320), P1b = [7864320, 9437184)
    //   float psums at ushort 9437184
    unsigned short* y0  = WS;
    unsigned short* D   = WS;                 // dw output (y0 slot, dead)
    unsigned short* P0a = WS + 3145728;
    unsigned short* P0b = WS + 4718592;
    unsigned short* P1a = WS + 6291456;
    unsigned short* P1b = WS + 7864320;
    float* p1 = (float*)(WS + 9437184);
    float* p2 = p1 + 256;
    float* p3 = p2 + 256;
    float* out = (float*)d_out;

    k_deform<<<dim3(8, 192), 256, 0, stream>>>(x, xr, ro, y0);
    k_pw<256><<<dim3(192, 2, 2), 256, 0, stream>>>(y0, wr, P0a, P0b);
    k_stats2<<<128, 256, 0, stream>>>(P0a, P0b, p1);
    k_dw2<<<1536, 256, 0, stream>>>(P0a, P0b, p1, gr, br, dw1, (ushort4*)D);
    k_pw<128><<<dim3(192, 2, 2), 256, 0, stream>>>(D, pw1, P1a, P1b);
    k_stats2<<<128, 256, 0, stream>>>(P1a, P1b, p2);
    k_dw2<<<1536, 256, 0, stream>>>(P1a, P1b, p2, g1, b1, dw2, (ushort4*)D);
    k_pw<128><<<dim3(192, 2, 2), 256, 0, stream>>>(D, pw2, P0a, P0b);
    k_stats2<<<128, 256, 0, stream>>>(P0a, P0b, p3);
    k_final2<<<1536, 256, 0, stream>>>(P0a, P0b, p3, g2, b2, (float4*)out);
}

// Round 19
// 170.456 us; speedup vs baseline: 1.5715x; 1.0112x over previous
//
#include <hip/hip_runtime.h>
#include <hip/hip_bf16.h>

#define HW    12288
#define Wimg  192
#define Himg  64
#define Wpad  194
#define Ppad  12804   // 66*194

// bf16 <-> fp32 helpers (RNE), header-independent
static __device__ __forceinline__ unsigned short f2bf(float f) {
    union { float f; unsigned int u; } v; v.f = f;
    unsigned int r = v.u + 0x7fffu + ((v.u >> 16) & 1u);
    return (unsigned short)(r >> 16);
}
static __device__ __forceinline__ float bf2f(unsigned short h) {
    union { unsigned int u; float f; } v; v.u = ((unsigned int)h) << 16;
    return v.f;
}
static __device__ __forceinline__ float bflo(unsigned int u) {
    union { unsigned int u; float f; } v; v.u = u << 16; return v.f;
}
static __device__ __forceinline__ float bfhi(unsigned int u) {
    union { unsigned int u; float f; } v; v.u = u & 0xffff0000u; return v.f;
}

// ---------------------------------------------------------------------------
// K1: deformable gather via LDS-staged windows (flat-space staging).
// R19: window staged as bf16 (15.4 KB LDS) + launch_bounds(256,6) ->
// 6 blocks/CU, the whole 1536-block grid resident in ONE round (was 4
// blocks/CU, 1.5 rounds).  Math identical to R15-R18 (exact flat-space
// replication incl. row-wrap targets).
// ---------------------------------------------------------------------------
__global__ __launch_bounds__(256, 6) void k_deform(
    const float* __restrict__ x,     // 256 x HW
    const float* __restrict__ xr,    // HW
    const float* __restrict__ rout,  // 256 x 9
    unsigned short* __restrict__ y0) // 256 x HW (bf16)
{
    __shared__ unsigned short s_x[32][240];  // 3 window rows x stride 80

    const int cblk = blockIdx.x;     // 0..7   (fastest -> XCD id)
    const int tile = blockIdx.y;     // 0..191
    const int tid  = threadIdx.x;
    const int pl   = tid & 63;
    const int wv   = __builtin_amdgcn_readfirstlane(tid >> 6);
    const int h    = tile / 3;
    const int w0   = (tile - h * 3) * 64;
    const int w    = w0 + pl;
    const int gp   = h * Wimg + w;

    int   li[6];
    float gw[6][3];
    const float off = 3.0f / (1.0f + expf(-xr[gp]));

    #pragma unroll
    for (int t = 0; t < 6; ++t) {
        const int xo = (t & 1) ? 1 : -1;
        const int yo = (t >> 1) - 1;
        float ov  = off * (float)xo;
        int   iv  = yo * Wpad;
        int   pre = (h + 1) * Wpad + (w + 1) + xo + iv;
        float after = (float)(pre + iv) + ov;
        int fl = (int)floorf(ov);
        int ce = (int)ceilf(ov);
        int av_f  = min(max(pre + fl + iv, 0), Ppad - 1);
        int av_f1 = min(max(av_f + xo,    0), Ppad - 1);
        int av_c  = min(max(pre + ce + iv, 0), Ppad - 1);
        int av_c1 = min(max(av_c + xo,    0), Ppad - 1);
        float wf  = fabsf(after - (float)av_f);
        float wf1 = fabsf((float)av_f1 - after);
        float wc1 = fabsf(after - (float)av_c1);
        float wc  = fabsf((float)av_c - after);
        float s1 = wf  * (1.0f / Wpad);
        float s2 = wc1 * (1.0f / Wpad);
        int   i4[4] = { av_f, av_f1, av_c1, av_c };
        float w4[4] = { s1 * wf, s1 * wf1, s2 * wc1, s2 * wc };
        int b = min(min(i4[0], i4[1]), min(i4[2], i4[3]));
        const int base = (h + 1 + 2 * yo) * Wpad + w0 - 4;
        li[t] = (t >> 1) * 80 + min(max(b - base, 0), 71);
        #pragma unroll
        for (int s = 0; s < 3; ++s) {
            float ws = 0.0f;
            #pragma unroll
            for (int j = 0; j < 4; ++j)
                ws += (i4[j] == b + s) ? w4[j] : 0.0f;
            int av = b + s;
            int r  = av / Wpad;
            int cc = av - r * Wpad;
            bool inb = (r >= 1) && (r <= Himg) && (cc >= 1) && (cc <= Wimg);
            gw[t][s] = inb ? ws : 0.0f;
        }
    }

    // stage the 3x74 flat windows for the block's 32 channels (bf16)
    const int jj = tid;
    int  xoff = 0;
    bool valid = false;
    int  rr = 0, jcol = 0;
    if (jj < 222) {
        rr   = jj / 74;
        jcol = jj - rr * 74;
        const int flat = (h + 1 + 2 * (rr - 1)) * Wpad + w0 - 4 + jcol;
        if (flat >= 0 && flat < Ppad) {
            const int r = flat / Wpad;
            const int c = flat - r * Wpad;
            valid = (r >= 1) && (r <= Himg) && (c >= 1) && (c <= Wimg);
            xoff  = valid ? ((r - 1) * Wimg + (c - 1)) : 0;
        }
    }
    const float* xb = x + (size_t)(cblk * 32) * HW;
    for (int c = 0; c < 32; ++c) {
        if (jj < 222) {
            float v = valid ? xb[(size_t)c * HW + xoff] : 0.0f;
            s_x[c][rr * 80 + jcol] = f2bf(v);
        }
    }
    __syncthreads();

    const int c0l = wv * 8;
    #pragma unroll 2
    for (int i = 0; i < 8; ++i) {
        const int cl = c0l + i;
        const unsigned short* sxc = s_x[cl];
        const float* rc = rout + (cblk * 32 + cl) * 9;
        float acc = 0.0f;
        #pragma unroll
        for (int t = 0; t < 6; ++t) {
            float part = gw[t][0] * bf2f(sxc[li[t]])
                       + gw[t][1] * bf2f(sxc[li[t] + 1])
                       + gw[t][2] * bf2f(sxc[li[t] + 2]);
            const int k = 3 * (t >> 1) + ((t & 1) ? 2 : 0);
            acc += rc[k] * part;
        }
        y0[(size_t)(cblk * 32 + cl) * HW + gp] = f2bf(acc);
    }
}

// ---------------------------------------------------------------------------
// Pointwise GEMM, split-K, bf16 in/out (R16-proven).
// ---------------------------------------------------------------------------
template <int CIN>
__global__ __launch_bounds__(256) void k_pw(
    const unsigned short* __restrict__ A,   // CIN x HW (bf16)
    const float* __restrict__ Wm,           // 128 x CIN (fp32)
    unsigned short* __restrict__ Zp0,
    unsigned short* __restrict__ Zp1)
{
    __shared__ float s_a[32][64];
    __shared__ float s_w[32][68];
    const int tid = threadIdx.x;
    const int tx  = tid & 15;
    const int ty  = tid >> 4;
    const int px0 = blockIdx.x * 64;
    const int o0  = blockIdx.y * 64;
    const int KH  = CIN / 2;
    const int cb0 = blockIdx.z * KH;
    unsigned short* __restrict__ Zp = blockIdx.z ? Zp1 : Zp0;

    float acc[4][4];
    #pragma unroll
    for (int i = 0; i < 4; ++i)
        #pragma unroll
        for (int j = 0; j < 4; ++j) acc[i][j] = 0.0f;

    const int arow = tid >> 3;
    const int acg  = tid & 7;
    const int wo = tid >> 5;
    const int wl = tid & 31;

    for (int cb = cb0; cb < cb0 + KH; cb += 32) {
        {
            const uint4* ap = (const uint4*)(A + (size_t)(cb + arow) * HW + px0);
            uint4 u = ap[acg];
            float4 lo = make_float4(bflo(u.x), bfhi(u.x), bflo(u.y), bfhi(u.y));
            float4 hi = make_float4(bflo(u.z), bfhi(u.z), bflo(u.w), bfhi(u.w));
            *(float4*)&s_a[arow][acg * 8]     = lo;
            *(float4*)&s_a[arow][acg * 8 + 4] = hi;
        }
        #pragma unroll
        for (int i = 0; i < 8; ++i)
            s_w[wl][wo + 8 * i] = Wm[(size_t)(o0 + wo + 8 * i) * CIN + cb + wl];
        __syncthreads();
        #pragma unroll
        for (int cc = 0; cc < 32; ++cc) {
            float4 a4 = *(const float4*)&s_a[cc][tx * 4];
            float4 w4 = *(const float4*)&s_w[cc][ty * 4];
            acc[0][0] += w4.x * a4.x; acc[0][1] += w4.x * a4.y;
            acc[0][2] += w4.x * a4.z; acc[0][3] += w4.x * a4.w;
            acc[1][0] += w4.y * a4.x; acc[1][1] += w4.y * a4.y;
            acc[1][2] += w4.y * a4.z; acc[1][3] += w4.y * a4.w;
            acc[2][0] += w4.z * a4.x; acc[2][1] += w4.z * a4.y;
            acc[2][2] += w4.z * a4.z; acc[2][3] += w4.z * a4.w;
            acc[3][0] += w4.w * a4.x; acc[3][1] += w4.w * a4.y;
            acc[3][2] += w4.w * a4.z; acc[3][3] += w4.w * a4.w;
        }
        __syncthreads();
    }

    #pragma unroll
    for (int i = 0; i < 4; ++i) {
        ushort4 v;
        v.x = f2bf(acc[i][0]); v.y = f2bf(acc[i][1]);
        v.z = f2bf(acc[i][2]); v.w = f2bf(acc[i][3]);
        *(ushort4*)&Zp[(size_t)(o0 + ty * 4 + i) * HW + px0 + tx * 4] = v;
    }
}

// ---------------------------------------------------------------------------
// BN stats over z = Zp0 + Zp1.  One block per channel, direct write.
// ---------------------------------------------------------------------------
__global__ __launch_bounds__(256) void k_stats2(
    const unsigned short* __restrict__ Zp0,
    const unsigned short* __restrict__ Zp1,
    float* __restrict__ psum)        // 128 x {sum,sumsq}
{
    __shared__ float s_s[4], s_q[4];
    const int c   = blockIdx.x;
    const int tid = threadIdx.x;
    const size_t base = (size_t)c * HW;
    const uint2* a4 = (const uint2*)(Zp0 + base);
    const uint2* b4 = (const uint2*)(Zp1 + base);
    float s = 0.0f, q = 0.0f;
    #pragma unroll
    for (int i = 0; i < 12; ++i) {
        uint2 a = a4[tid + i * 256];
        uint2 b = b4[tid + i * 256];
        float v0 = bflo(a.x) + bflo(b.x);
        float v1 = bfhi(a.x) + bfhi(b.x);
        float v2 = bflo(a.y) + bflo(b.y);
        float v3 = bfhi(a.y) + bfhi(b.y);
        s += v0 + v1 + v2 + v3;
        q += v0 * v0 + v1 * v1 + v2 * v2 + v3 * v3;
    }
    #pragma unroll
    for (int off = 32; off > 0; off >>= 1) {
        s += __shfl_down(s, off, 64);
        q += __shfl_down(q, off, 64);
    }
    if ((tid & 63) == 0) { s_s[tid >> 6] = s; s_q[tid >> 6] = q; }
    __syncthreads();
    if (tid == 0) {
        psum[2 * c]     = s_s[0] + s_s[1] + s_s[2] + s_s[3];
        psum[2 * c + 1] = s_q[0] + s_q[1] + s_q[2] + s_q[3];
    }
}

// ---------------------------------------------------------------------------
// Fused: z = Zp0+Zp1 (inline), BN+LeakyReLU, depthwise 3x3 (zero pad).
// ---------------------------------------------------------------------------
__global__ __launch_bounds__(256) void k_dw2(
    const unsigned short* __restrict__ Zp0,
    const unsigned short* __restrict__ Zp1,
    const float* __restrict__ psum,  // 128 x {sum,sumsq}
    const float* __restrict__ g,
    const float* __restrict__ b,
    const float* __restrict__ dwgt,  // 128 x 9
    ushort4* __restrict__ D)
{
    const int t  = blockIdx.x * 256 + threadIdx.x;  // 0..393215
    const int c  = t / 3072;
    const int gg = t - c * 3072;
    const int h  = gg / 48;
    const int w0 = (gg - h * 48) << 2;

    const float s   = psum[2 * c];
    const float q   = psum[2 * c + 1];
    const float mu  = s * (1.0f / HW);
    const float var = q * (1.0f / HW) - mu * mu;
    const float sc  = g[c] * rsqrtf(var + 1e-5f);
    const float sh  = b[c] - mu * sc;

    float wk[9];
    #pragma unroll
    for (int k = 0; k < 9; ++k) wk[k] = dwgt[c * 9 + k];

    const unsigned short* z0 = Zp0 + (size_t)c * HW;
    const unsigned short* z1 = Zp1 + (size_t)c * HW;
    float v[3][6];
    #pragma unroll
    for (int ky = 0; ky < 3; ++ky) {
        const int hh  = h + ky - 1;
        const bool rin = (hh >= 0) && (hh < Himg);
        #pragma unroll
        for (int j = 0; j < 6; ++j) {
            const int ww = w0 - 1 + j;
            const bool in = rin && (ww >= 0) && (ww < Wimg);
            float z = in ? (bf2f(z0[hh * Wimg + ww]) + bf2f(z1[hh * Wimg + ww]))
                         : 0.0f;
            float y = z * sc + sh;
            y = (y >= 0.0f) ? y : 0.01f * y;
            v[ky][j] = in ? y : 0.0f;
        }
    }

    ushort4 o;
    float oo[4];
    #pragma unroll
    for (int j = 0; j < 4; ++j) {
        float a = 0.0f;
        #pragma unroll
        for (int ky = 0; ky < 3; ++ky)
            #pragma unroll
            for (int kx = 0; kx < 3; ++kx)
                a += wk[ky * 3 + kx] * v[ky][j + kx];
        oo[j] = a;
    }
    o.x = f2bf(oo[0]); o.y = f2bf(oo[1]); o.z = f2bf(oo[2]); o.w = f2bf(oo[3]);
    D[t] = o;
}

// ---------------------------------------------------------------------------
// Final: z = Zp0+Zp1, BN+LeakyReLU, fp32 out.  grid = 1536.
// ---------------------------------------------------------------------------
__global__ __launch_bounds__(256) void k_final2(
    const unsigned short* __restrict__ Zp0,
    const unsigned short* __restrict__ Zp1,
    const float* __restrict__ psum,
    const float* __restrict__ g,
    const float* __restrict__ b,
    float4* __restrict__ out)
{
    const int f = blockIdx.x * 256 + threadIdx.x;
    const int c = f / 3072;

    const float s   = psum[2 * c];
    const float q   = psum[2 * c + 1];
    const float mu  = s * (1.0f / HW);
    const float var = q * (1.0f / HW) - mu * mu;
    const float sc  = g[c] * rsqrtf(var + 1e-5f);
    const float sh  = b[c] - mu * sc;

    uint2 a = ((const uint2*)Zp0)[f];
    uint2 d = ((const uint2*)Zp1)[f];
    float4 v;
    v.x = (bflo(a.x) + bflo(d.x)) * sc + sh; v.x = (v.x >= 0.0f) ? v.x : 0.01f * v.x;
    v.y = (bfhi(a.x) + bfhi(d.x)) * sc + sh; v.y = (v.y >= 0.0f) ? v.y : 0.01f * v.y;
    v.z = (bflo(a.y) + bflo(d.y)) * sc + sh; v.z = (v.z >= 0.0f) ? v.z : 0.01f * v.z;
    v.w = (bfhi(a.y) + bfhi(d.y)) * sc + sh; v.w = (v.w >= 0.0f) ? v.w : 0.01f * v.w;
    out[f] = v;
}

// ---------------------------------------------------------------------------
extern "C" void kernel_launch(void* const* d_in, const int* in_sizes, int n_in,
                              void* d_out, int out_size, void* d_ws, size_t ws_size,
                              hipStream_t stream) {
    const float* x   = (const float*)d_in[0];
    const float* xr  = (const float*)d_in[1];
    const float* ro  = (const float*)d_in[2];
    const float* wr  = (const float*)d_in[3];
    const float* gr  = (const float*)d_in[4];
    const float* br  = (const float*)d_in[5];
    const float* dw1 = (const float*)d_in[6];
    const float* pw1 = (const float*)d_in[7];
    const float* g1  = (const float*)d_in[8];
    const float* b1  = (const float*)d_in[9];
    const float* dw2 = (const float*)d_in[10];
    const float* pw2 = (const float*)d_in[11];
    const float* g2  = (const float*)d_in[12];
    const float* b2  = (const float*)d_in[13];

    unsigned short* WS = (unsigned short*)d_ws;
    unsigned short* y0  = WS;
    unsigned short* D   = WS;                 // dw output (y0 slot, dead)
    unsigned short* P0a = WS + 3145728;
    unsigned short* P0b = WS + 4718592;
    unsigned short* P1a = WS + 6291456;
    unsigned short* P1b = WS + 7864320;
    float* p1 = (float*)(WS + 9437184);
    float* p2 = p1 + 256;
    float* p3 = p2 + 256;
    float* out = (float*)d_out;

    k_deform<<<dim3(8, 192), 256, 0, stream>>>(x, xr, ro, y0);
    k_pw<256><<<dim3(192, 2, 2), 256, 0, stream>>>(y0, wr, P0a, P0b);
    k_stats2<<<128, 256, 0, stream>>>(P0a, P0b, p1);
    k_dw2<<<1536, 256, 0, stream>>>(P0a, P0b, p1, gr, br, dw1, (ushort4*)D);
    k_pw<128><<<dim3(192, 2, 2), 256, 0, stream>>>(D, pw1, P1a, P1b);
    k_stats2<<<128, 256, 0, stream>>>(P1a, P1b, p2);
    k_dw2<<<1536, 256, 0, stream>>>(P1a, P1b, p2, g1, b1, dw2, (ushort4*)D);
    k_pw<128><<<dim3(192, 2, 2), 256, 0, stream>>>(D, pw2, P0a, P0b);
    k_stats2<<<128, 256, 0, stream>>>(P0a, P0b, p3);
    k_final2<<<1536, 256, 0, stream>>>(P0a, P0b, p3, g2, b2, (float4*)out);
}